// Round 6
// baseline (922.476 us; speedup 1.0000x reference)
//
#include <hip/hip_runtime.h>

// N=512 state dim, L=16384 steps, chunk T=1024, P=16 chunks.
#define NDIM 512
#define LSEQ 16384
#define TCH  1024
#define PCH  16
#define NB   256                     // persistent grid: 1 block/CU nominal;
                                     // capacity 2/CU (LDS 18.4KB, VGPR<=256)
#define DTF  (1.0f/16384.0f)
#define DT2F (0.5f/16384.0f)

__device__ __forceinline__ float wave_reduce(float v) {
#pragma unroll
    for (int off = 32; off; off >>= 1) v += __shfl_xor(v, off, 64);
    return v;
}

// ---------------------------------------------------------------------------
// grid_barrier: monotone-counter barrier. Every block increments once per
// call; all blocks spin until cnt reaches epoch*NB. Device-scope atomics +
// __threadfence (agent acquire/release) per G16. Bounded spin: a bug gives a
// wrong answer, never a hang.
// ---------------------------------------------------------------------------
__device__ __forceinline__ void grid_barrier(unsigned* cnt, unsigned target) {
    __syncthreads();
    if (threadIdx.x == 0) {
        __threadfence();                       // release our writes
        atomicAdd(cnt, 1u);
        unsigned guard = 0;
        while (atomicAdd(cnt, 0u) < target) {
            __builtin_amdgcn_s_sleep(2);
            if (++guard > (1u << 24)) break;
        }
        __threadfence();                       // acquire others' writes
    }
    __syncthreads();
}

// ---------------------------------------------------------------------------
// gkt_core: wave-task K-split GEMM tile. 32x32 output tile = one block;
// wave w covers k in [w*K/4,(w+1)*K/4) with private LDS staging; one block
// barrier + cross-wave reduce. M,N mult of 32, K mult 64. Trailing
// __syncthreads makes back-to-back calls safe.
// ---------------------------------------------------------------------------
__device__ __forceinline__ void gkt_core(float* __restrict__ smem,
    const float* __restrict__ A, int lda, const float* __restrict__ B, int ldb,
    float* __restrict__ D, int ldd, int ntx, int tile_id, int K, float alpha)
{
    const int tid  = threadIdx.x;
    const int w    = tid >> 6;
    const int lane = tid & 63;
    const int ty = lane >> 3, tx = lane & 7;
    const int ty_t = tile_id / ntx, tx_t = tile_id % ntx;
    const int row0 = ty_t * 32, col0 = tx_t * 32;

    float* As = smem + w * 1152;          // As[k][r] = As[k*36 + r]
    float* Bs = As + 576;                 // Bs[k][c] = Bs[k*36 + c]

    const int Kc    = K >> 2;
    const int steps = Kc >> 4;
    const int kbase = w * Kc;

    float acc[4][4] = {};

    for (int s = 0; s < steps; ++s) {
        const int kb = kbase + s * 16;
#pragma unroll
        for (int i = 0; i < 2; ++i) {     // stage A (transposed)
            int idx = lane + 64 * i;
            int r = idx >> 2, cg2 = (idx & 3) * 4;
            float4 v = *(const float4*)(A + (size_t)(row0 + r) * lda + kb + cg2);
            As[(cg2 + 0) * 36 + r] = v.x; As[(cg2 + 1) * 36 + r] = v.y;
            As[(cg2 + 2) * 36 + r] = v.z; As[(cg2 + 3) * 36 + r] = v.w;
        }
#pragma unroll
        for (int i = 0; i < 2; ++i) {     // stage B
            int idx = lane + 64 * i;
            int kr = idx >> 3, cg2 = (idx & 7) * 4;
            *(float4*)(Bs + kr * 36 + cg2) =
                *(const float4*)(B + (size_t)(kb + kr) * ldb + col0 + cg2);
        }
        __syncthreads();
#pragma unroll
        for (int kk = 0; kk < 16; ++kk) {
            float4 a = *(const float4*)(As + kk * 36 + 4 * ty);
            float4 b = *(const float4*)(Bs + kk * 36 + 4 * tx);
            acc[0][0] += a.x * b.x; acc[0][1] += a.x * b.y; acc[0][2] += a.x * b.z; acc[0][3] += a.x * b.w;
            acc[1][0] += a.y * b.x; acc[1][1] += a.y * b.y; acc[1][2] += a.y * b.z; acc[1][3] += a.y * b.w;
            acc[2][0] += a.z * b.x; acc[2][1] += a.z * b.y; acc[2][2] += a.z * b.z; acc[2][3] += a.z * b.w;
            acc[3][0] += a.w * b.x; acc[3][1] += a.w * b.y; acc[3][2] += a.w * b.z; acc[3][3] += a.w * b.w;
        }
        __syncthreads();
    }

    float* red = smem + w * 1152;
#pragma unroll
    for (int i = 0; i < 4; ++i)
        *(float4*)(red + (4 * ty + i) * 32 + 4 * tx) =
            make_float4(acc[i][0], acc[i][1], acc[i][2], acc[i][3]);
    __syncthreads();

    float4 s0 = *(const float4*)(smem + 0 * 1152 + tid * 4);
    float4 s1 = *(const float4*)(smem + 1 * 1152 + tid * 4);
    float4 s2 = *(const float4*)(smem + 2 * 1152 + tid * 4);
    float4 s3 = *(const float4*)(smem + 3 * 1152 + tid * 4);
    float4 r4 = make_float4(alpha * (s0.x + s1.x + s2.x + s3.x),
                            alpha * (s0.y + s1.y + s2.y + s3.y),
                            alpha * (s0.z + s1.z + s2.z + s3.z),
                            alpha * (s0.w + s1.w + s2.w + s3.w));
    int r = tid >> 3, c = (tid & 7) * 4;
    *(float4*)(D + (size_t)(row0 + r) * ldd + col0 + c) = r4;
    __syncthreads();
}

// ---------------------------------------------------------------------------
// diag_block_inv: invert 64x64 diagonal block `blk` of M = I - dt/2*A into W.
// All 256 threads stage; wave 0 solves (lane j owns column j of the inverse).
// ---------------------------------------------------------------------------
__device__ void diag_block_inv(float* smemf, const float* __restrict__ A,
                               float* __restrict__ W, int blk)
{
    float (*sh)[65] = (float (*)[65])smemf;
    const int tid = threadIdx.x;
    const int base = blk * 64;
    for (int idx = tid; idx < 4096; idx += 256) {
        int r = idx >> 6, c = idx & 63;
        sh[r][c] = ((r == c) ? 1.f : 0.f)
                 - DT2F * A[(size_t)(base + r) * NDIM + base + c];
    }
    __syncthreads();
    if (tid < 64) {
        const int lane = tid;
        float xcol[64];
#pragma unroll
        for (int i = 0; i < 64; ++i) {
            float dot = 0.f;
            for (int k = 0; k < i; ++k) dot += sh[i][k] * xcol[k];
            xcol[i] = (((lane == i) ? 1.f : 0.f) - dot) / sh[i][i];
        }
        for (int k = 0; k < 64; ++k)
            W[(size_t)(base + k) * NDIM + base + lane] = xcol[k];
    }
    __syncthreads();
}

// ---------------------------------------------------------------------------
// mega: the whole pipeline, one persistent launch with manual grid barriers.
// ---------------------------------------------------------------------------
__global__ __launch_bounds__(256, 2) void mega(
    const float* __restrict__ x, const float* __restrict__ hs,
    const float* __restrict__ A, const float* __restrict__ Bv,
    const float* __restrict__ C, float* __restrict__ out,
    float* __restrict__ ws, unsigned* __restrict__ cnt)
{
    __shared__ float smem[4608];
    const int bid = blockIdx.x, tid = threadIdx.x;
    const int w = tid >> 6, lane = tid & 63;
    unsigned ep = 0;

    const int MM = NDIM * NDIM;
    float* Ab = ws;
    float* P0 = Ab + MM;  float* P1 = P0 + MM;
    float* GA = P1 + MM;  float* GB = GA + MM;    // Ab^1024, Ab^2048
    float* GC = GB + MM;  float* GD = GC + MM;    // Ab^4096, Ab^8192
    float* V      = GD + MM;                      // 512 x 1024 (col j = v_j)
    float* Crows  = V + NDIM * TCH;               // 1024 x 512 (row j = c_j)
    float* CrowsS = Crows + TCH * NDIM;           // 1024 x 512 (aliases W)
    float* kv     = CrowsS + TCH * NDIM;          // 1024
    float* Bbc    = kv + TCH;                     // 512
    float* U      = Bbc + NDIM;                   // 16 x 512
    float* Z0     = U + PCH * NDIM;               // 16 x 512
    float* Z1     = Z0 + PCH * NDIM;              // 16 x 512
    float* Hmat   = Z1 + PCH * NDIM;              // 16 x 512
    float* W = CrowsS;   // W dead after phase C; CrowsS written at r>=10
    float* T = P0;       // T dead after pair level 256; P0 written at r=0

    // ---- phase A: zero strict-upper W (benign 0==0 race on diag blocks)
    //               + invert 8 diagonal blocks ----
    for (int idx = bid * 256 + tid; idx < MM; idx += NB * 256) {
        int i = idx >> 9, j = idx & 511;
        if (j > i) W[idx] = 0.f;
    }
    if (bid < 8) diag_block_inv(smem, A, W, bid);
    ep++; grid_barrier(cnt, ep * NB);

    // ---- phase B: block-doubling combine W21 = dt/2 * W22 @ (A21 @ W11) ----
    for (int s = 64; s <= 256; s <<= 1) {
        const int tiles = (s >> 5) * (s >> 5);
        const int np = NDIM / (2 * s);
        for (int t = bid; t < np * tiles; t += NB) {
            int pr = t / tiles, tl = t % tiles, o = pr * 2 * s;
            gkt_core(smem, A + (size_t)(o + s) * NDIM + o, NDIM,
                     W + (size_t)o * NDIM + o, NDIM,
                     T + (size_t)(o + s) * NDIM + o, NDIM, s >> 5, tl, s, 1.f);
        }
        ep++; grid_barrier(cnt, ep * NB);
        for (int t = bid; t < np * tiles; t += NB) {
            int pr = t / tiles, tl = t % tiles, o = pr * 2 * s;
            gkt_core(smem, W + (size_t)(o + s) * NDIM + (o + s), NDIM,
                     T + (size_t)(o + s) * NDIM + o, NDIM,
                     W + (size_t)(o + s) * NDIM + o, NDIM, s >> 5, tl, s, DT2F);
        }
        ep++; grid_barrier(cnt, ep * NB);
    }

    // ---- phase C: Ab = 2W - I ; Bb = dt*W@Bv -> V[:,0],Bbc ; Crows[0]=C ----
    {
        int idx = bid * 256 + tid;            // NB*256 == MM/4 exactly
        int i = idx >> 7, j0 = (idx & 127) << 2;
        float4 wv = *(const float4*)(W + (size_t)i * NDIM + j0);
        float4 r = make_float4(2.f * wv.x, 2.f * wv.y, 2.f * wv.z, 2.f * wv.w);
        if (i == j0)          r.x -= 1.f;
        else if (i == j0 + 1) r.y -= 1.f;
        else if (i == j0 + 2) r.z -= 1.f;
        else if (i == j0 + 3) r.w -= 1.f;
        *(float4*)(Ab + (size_t)i * NDIM + j0) = r;
    }
    if (bid < 128) {                          // prep: wave per row
        int i = bid * 4 + w;
        float s = 0.f;
#pragma unroll
        for (int c2 = 0; c2 < 2; ++c2) {
            int k = c2 * 256 + lane * 4;
            float4 wv = *(const float4*)(W + (size_t)i * NDIM + k);
            float4 b4 = *(const float4*)(Bv + k);
            s += wv.x * b4.x + wv.y * b4.y + wv.z * b4.z + wv.w * b4.w;
        }
        s = wave_reduce(s);
        if (lane == 0) { float bb = DTF * s; V[(size_t)i * TCH] = bb; Bbc[i] = bb; }
    } else if (bid == 128) {
        Crows[tid] = C[tid]; Crows[tid + 256] = C[tid + 256];
    }
    ep++; grid_barrier(cnt, ep * NB);

    // ---- phase D: 13 doubling rounds (squaring + V/Crows; post work rides
    //      in spare tasks at r>=10: CrowsS=Crows@Ab, kv=Crows.Bb, U build) ----
    const float* gsrc = Ab;
    float* gouts[13] = {P0, P1, P0, P1, P0, P1, P0, P1, P0, GA, GB, GC, GD};
    for (int r = 0; r < 13; ++r) {
        const int m = 1 << r;
        float* gdst = gouts[r];
        int nextra;
        if (m < 32)        nextra = m * 10;                // V-small + C-small
        else if (m < TCH)  nextra = 2 * ((m >> 5) * 16);   // V tiles + C tiles
        else               nextra = 939;                   // post quota
        const int ntasks = 256 + nextra;
        for (int t = bid; t < ntasks; t += NB) {
            if (t < 256) {
                gkt_core(smem, gsrc, NDIM, gsrc, NDIM, gdst, NDIM, 16, t, NDIM, 1.f);
            } else {
                int e = t - 256;
                if (m < 32) {
                    if (e < m * 8) {                       // V[:, m+j] = g @ V[:, j]
                        int j = e >> 3, slab = e & 7;
                        for (int k = tid; k < NDIM; k += 256)
                            smem[k] = V[(size_t)k * TCH + j];
                        __syncthreads();
                        for (int d = 0; d < 16; ++d) {
                            int i = slab * 64 + w * 16 + d;
                            float ssum = 0.f;
#pragma unroll
                            for (int c2 = 0; c2 < 2; ++c2) {
                                int k = c2 * 256 + lane * 4;
                                float4 g4 = *(const float4*)(gsrc + (size_t)i * NDIM + k);
                                float4 v4 = *(const float4*)(smem + k);
                                ssum += g4.x * v4.x + g4.y * v4.y + g4.z * v4.z + g4.w * v4.w;
                            }
                            ssum = wave_reduce(ssum);
                            if (lane == 0) V[(size_t)i * TCH + m + j] = ssum;
                        }
                        __syncthreads();
                    } else {                               // Crows[m+j] = Crows[j] @ g
                        int e2 = e - m * 8;
                        int j = e2 >> 1, c = ((e2 & 1) << 8) + tid;
                        const float* cr = Crows + (size_t)j * NDIM;
                        float acc = 0.f;
#pragma unroll 8
                        for (int k = 0; k < NDIM; ++k)
                            acc += cr[k] * gsrc[(size_t)k * NDIM + c];
                        Crows[(size_t)(m + j) * NDIM + c] = acc;
                    }
                } else if (m < TCH) {
                    const int nv = (m >> 5) * 16;
                    if (e < nv)
                        gkt_core(smem, gsrc, NDIM, V, TCH, V + m, TCH,
                                 m >> 5, e, NDIM, 1.f);
                    else
                        gkt_core(smem, Crows, NDIM, gsrc, NDIM,
                                 Crows + (size_t)m * NDIM, NDIM, 16, e - nv, NDIM, 1.f);
                } else {
                    int k = e * 3 + (r - 10);              // stride-3 interleave
                    if (k < 2816) {
                        if (k < 512) {                     // CrowsS tile
                            gkt_core(smem, Crows, NDIM, Ab, NDIM, CrowsS, NDIM,
                                     16, k, NDIM, 1.f);
                        } else if (k < 768) {              // kv group
                            int j = (k - 512) * 4 + w;
                            const float* cr = Crows + (size_t)j * NDIM;
                            float dot = 0.f;
#pragma unroll
                            for (int c2 = 0; c2 < 2; ++c2) {
                                int kk = c2 * 256 + lane * 4;
                                float4 cv = *(const float4*)(cr + kk);
                                float4 bv = *(const float4*)(Bbc + kk);
                                dot += cv.x * bv.x + cv.y * bv.y + cv.z * bv.z + cv.w * bv.w;
                            }
                            dot = wave_reduce(dot);
                            if (lane == 0) kv[j] = dot;
                        } else {                           // U group (+GA@h0 at p==0)
                            int wid = (k - 768) * 4 + w;   // 0..8191
                            int p = wid & (PCH - 1), i = wid >> 4;
                            const float* vr = V + (size_t)i * TCH;
                            const float* xc = x + p * TCH;
                            float s = 0.f;
#pragma unroll
                            for (int r2 = 0; r2 < 16; ++r2) {
                                int tt = (r2 << 6) + lane;
                                s += vr[TCH - 1 - tt] * xc[tt];
                            }
                            if (p == 0) {
                                const float* gr = GA + (size_t)i * NDIM;
#pragma unroll
                                for (int r2 = 0; r2 < 8; ++r2) {
                                    int kk = (r2 << 6) + lane;
                                    s += gr[kk] * hs[kk];
                                }
                            }
                            s = wave_reduce(s);
                            if (lane == 0) U[(size_t)p * NDIM + i] = s;
                        }
                    }
                }
            }
        }
        ep++; grid_barrier(cnt, ep * NB);
        gsrc = gdst;
    }

    // ---- phase E: Kogge-Stone chunk scan, offsets 1,2,4,8 ----
    {
        const float* Gs[4]  = {GA, GB, GC, GD};
        const float* Zi[4]  = {U, Z0, Z1, Z0};
        float*       Zo[4]  = {Z0, Z1, Z0, Z1};
        const int    os4[4] = {1, 2, 4, 8};
#pragma unroll
        for (int sr = 0; sr < 4; ++sr) {
            const float* G = Gs[sr]; const float* Zin = Zi[sr]; float* Zout = Zo[sr];
            const int o = os4[sr];
            for (int vt = bid; vt < 2048; vt += NB) {
                int wid = vt * 4 + w;
                int p = wid & (PCH - 1), i = wid >> 4;
                float dot = 0.f;
                if (p >= o) {
                    const float* gr = G + (size_t)i * NDIM;
                    const float* zc = Zin + (size_t)(p - o) * NDIM;
#pragma unroll
                    for (int r2 = 0; r2 < 8; ++r2) {
                        int k = (r2 << 6) + lane;
                        dot += gr[k] * zc[k];
                    }
                    dot = wave_reduce(dot);
                }
                if (lane == 0) {
                    float z = Zin[(size_t)p * NDIM + i] + dot;
                    Zout[(size_t)p * NDIM + i] = z;
                    if (sr == 3) {
                        if (p < PCH - 1) Hmat[(size_t)(p + 1) * NDIM + i] = z;
                        else             out[LSEQ + i] = z;
                        if (p == 0) Hmat[i] = hs[i];
                    }
                }
            }
            ep++; grid_barrier(cnt, ep * NB);
        }
    }

    // ---- phase F: emit y = c_{s+1}.h_p + causal conv ----
    for (int vt = bid; vt < 4096; vt += NB) {
        int wid = vt * 4 + w;
        int p = wid & (PCH - 1), s2 = wid >> 4;
        const float* cr = CrowsS + (size_t)s2 * NDIM;
        const float* hp = Hmat + (size_t)p * NDIM;
        float dot = 0.f;
#pragma unroll
        for (int r2 = 0; r2 < 2; ++r2) {
            int k = r2 * 256 + lane * 4;
            float4 cv = *(const float4*)(cr + k);
            float4 hv = *(const float4*)(hp + k);
            dot += cv.x * hv.x + cv.y * hv.y + cv.z * hv.z + cv.w * hv.w;
        }
        const float* xc = x + p * TCH;
        int rmax = s2 >> 6;
        for (int r2 = 0; r2 <= rmax; ++r2) {
            int t = (r2 << 6) + lane;
            if (t <= s2) dot += kv[s2 - t] * xc[t];
        }
        dot = wave_reduce(dot);
        if (lane == 0) out[p * TCH + s2] = dot;
    }
}

// ---------------------------------------------------------------------------
extern "C" void kernel_launch(void* const* d_in, const int* in_sizes, int n_in,
                              void* d_out, int out_size, void* d_ws, size_t ws_size,
                              hipStream_t stream)
{
    const float* x  = (const float*)d_in[0];
    const float* hs = (const float*)d_in[1];
    const float* A  = (const float*)d_in[2];
    const float* Bv = (const float*)d_in[3];
    const float* C  = (const float*)d_in[4];
    float* out = (float*)d_out;                 // [y (16384) | h_final (512)]
    float* ws  = (float*)d_ws;

    // barrier counter right after the float workspace (see mega's layout):
    // 7*MM + V + Crows + CrowsS + kv + Bbc + 4*(PCH*NDIM)
    const size_t MM = (size_t)NDIM * NDIM;
    const size_t cnt_off = 7 * MM + 3 * (size_t)NDIM * TCH
                         + TCH + NDIM + 4 * (size_t)PCH * NDIM;   // 3442176
    unsigned* cnt = (unsigned*)(ws + cnt_off);
    hipMemsetAsync(cnt, 0, 256, stream);

    mega<<<NB, 256, 0, stream>>>(x, hs, A, Bv, C, out, ws, cnt);
}

// Round 7
// 841.218 us; speedup vs baseline: 1.0966x; 1.0966x over previous
//
#include <hip/hip_runtime.h>

// N=512 state dim, L=16384 steps, chunk T=1024, P=16 chunks.
#define NDIM 512
#define LSEQ 16384
#define TCH  1024
#define PCH  16
#define NB   256                     // persistent grid: 1 block/CU
#define NTH  512                     // 8 waves/block -> 2 waves/SIMD

#define DTF  (1.0f/16384.0f)
#define DT2F (0.5f/16384.0f)

__device__ __forceinline__ float wave_reduce(float v) {
#pragma unroll
    for (int off = 32; off; off >>= 1) v += __shfl_xor(v, off, 64);
    return v;
}

// ---------------------------------------------------------------------------
// grid_barrier: arrival = one agent-scope fetch_add per block; spin = relaxed
// agent-scope LOADS (no RMW -> no serialization; this was round 6's 500 us).
// Bounded spin: a bug gives a wrong answer, never a hang.
// ---------------------------------------------------------------------------
__device__ __forceinline__ void grid_barrier(unsigned* cnt, unsigned target) {
    __syncthreads();
    if (threadIdx.x == 0) {
        __threadfence();
        __hip_atomic_fetch_add(cnt, 1u, __ATOMIC_RELAXED, __HIP_MEMORY_SCOPE_AGENT);
        unsigned guard = 0;
        while (__hip_atomic_load(cnt, __ATOMIC_RELAXED,
                                 __HIP_MEMORY_SCOPE_AGENT) < target) {
            __builtin_amdgcn_s_sleep(1);
            if (++guard > (1u << 22)) break;
        }
        __threadfence();
    }
    __syncthreads();
}

// ---------------------------------------------------------------------------
// gkt_core: 8-wave K-split GEMM tile. One 32x32 output tile per block; wave w
// covers k-chunk [w*K/8, (w+1)*K/8) with private LDS staging; one barrier +
// cross-wave reduce (tid<256). K mult of 128, or K==64 (wave-duplication:
// waves 4..7 mirror 0..3; exact duplicates, alpha scaled by 0.5).
// Trailing __syncthreads makes back-to-back calls safe.
// ---------------------------------------------------------------------------
__device__ __forceinline__ void gkt_core(float* __restrict__ smem,
    const float* __restrict__ A, int lda, const float* __restrict__ B, int ldb,
    float* __restrict__ D, int ldd, int ntx, int tile_id, int K, float alpha)
{
    const int tid  = threadIdx.x;
    const int w    = tid >> 6;
    const int lane = tid & 63;
    const int ty = lane >> 3, tx = lane & 7;
    const int row0 = (tile_id / ntx) * 32, col0 = (tile_id % ntx) * 32;

    float* As = smem + w * 1152;          // As[k][r] = As[k*36 + r]
    float* Bs = As + 576;                 // Bs[k][c] = Bs[k*36 + c]

    const bool dup = (K < 128);           // K==64 path
    const int  Kc    = dup ? 16 : (K >> 3);
    const int  steps = Kc >> 4;
    const int  kbase = (dup ? (w & 3) : w) * Kc;
    const float aEff = dup ? alpha * 0.5f : alpha;

    float acc[4][4] = {};

    for (int s = 0; s < steps; ++s) {
        const int kb = kbase + s * 16;
#pragma unroll
        for (int i = 0; i < 2; ++i) {     // stage A (transposed): 32 rows x 16 k
            int idx = lane + 64 * i;
            int r = idx >> 2, cg2 = (idx & 3) * 4;
            float4 v = *(const float4*)(A + (size_t)(row0 + r) * lda + kb + cg2);
            As[(cg2 + 0) * 36 + r] = v.x; As[(cg2 + 1) * 36 + r] = v.y;
            As[(cg2 + 2) * 36 + r] = v.z; As[(cg2 + 3) * 36 + r] = v.w;
        }
#pragma unroll
        for (int i = 0; i < 2; ++i) {     // stage B: 16 k x 32 cols
            int idx = lane + 64 * i;
            int kr = idx >> 3, cg2 = (idx & 7) * 4;
            *(float4*)(Bs + kr * 36 + cg2) =
                *(const float4*)(B + (size_t)(kb + kr) * ldb + col0 + cg2);
        }
        __syncthreads();
#pragma unroll
        for (int kk = 0; kk < 16; ++kk) {
            float4 a = *(const float4*)(As + kk * 36 + 4 * ty);
            float4 b = *(const float4*)(Bs + kk * 36 + 4 * tx);
            acc[0][0] += a.x * b.x; acc[0][1] += a.x * b.y; acc[0][2] += a.x * b.z; acc[0][3] += a.x * b.w;
            acc[1][0] += a.y * b.x; acc[1][1] += a.y * b.y; acc[1][2] += a.y * b.z; acc[1][3] += a.y * b.w;
            acc[2][0] += a.z * b.x; acc[2][1] += a.z * b.y; acc[2][2] += a.z * b.z; acc[2][3] += a.z * b.w;
            acc[3][0] += a.w * b.x; acc[3][1] += a.w * b.y; acc[3][2] += a.w * b.z; acc[3][3] += a.w * b.w;
        }
        __syncthreads();
    }

    float* red = smem + w * 1152;         // 32x32 partial per wave
#pragma unroll
    for (int i = 0; i < 4; ++i)
        *(float4*)(red + (4 * ty + i) * 32 + 4 * tx) =
            make_float4(acc[i][0], acc[i][1], acc[i][2], acc[i][3]);
    __syncthreads();

    if (tid < 256) {
        float4 s4 = make_float4(0.f, 0.f, 0.f, 0.f);
#pragma unroll
        for (int rr = 0; rr < 8; ++rr) {
            float4 p = *(const float4*)(smem + rr * 1152 + tid * 4);
            s4.x += p.x; s4.y += p.y; s4.z += p.z; s4.w += p.w;
        }
        s4.x *= aEff; s4.y *= aEff; s4.z *= aEff; s4.w *= aEff;
        int r = tid >> 3, c = (tid & 7) * 4;
        *(float4*)(D + (size_t)(row0 + r) * ldd + col0 + c) = s4;
    }
    __syncthreads();
}

// ---------------------------------------------------------------------------
// diag_block_inv: invert 64x64 diagonal block `blk` of M = I - dt/2*A into W.
// All threads stage; wave 0 solves (lane j owns column j of the inverse).
// ---------------------------------------------------------------------------
__device__ void diag_block_inv(float* smemf, const float* __restrict__ A,
                               float* __restrict__ W, int blk)
{
    float (*sh)[65] = (float (*)[65])smemf;
    const int tid = threadIdx.x;
    const int base = blk * 64;
    for (int idx = tid; idx < 4096; idx += NTH) {
        int r = idx >> 6, c = idx & 63;
        sh[r][c] = ((r == c) ? 1.f : 0.f)
                 - DT2F * A[(size_t)(base + r) * NDIM + base + c];
    }
    __syncthreads();
    if (tid < 64) {
        const int lane = tid;
        float xcol[64];
#pragma unroll
        for (int i = 0; i < 64; ++i) {
            float dot = 0.f;
            for (int k = 0; k < i; ++k) dot += sh[i][k] * xcol[k];
            xcol[i] = (((lane == i) ? 1.f : 0.f) - dot) / sh[i][i];
        }
        for (int k = 0; k < 64; ++k)
            W[(size_t)(base + k) * NDIM + base + lane] = xcol[k];
    }
    __syncthreads();
}

// ---------------------------------------------------------------------------
// mega: the whole pipeline, one persistent launch with manual grid barriers.
// ---------------------------------------------------------------------------
__global__ __launch_bounds__(NTH, 1) void mega(
    const float* __restrict__ x, const float* __restrict__ hs,
    const float* __restrict__ A, const float* __restrict__ Bv,
    const float* __restrict__ C, float* __restrict__ out,
    float* __restrict__ ws, unsigned* __restrict__ cnt)
{
    __shared__ float smem[9216];          // 8 waves x 1152 floats = 36.9 KB
    const int bid = blockIdx.x, tid = threadIdx.x;
    const int w = tid >> 6, lane = tid & 63;
    unsigned ep = 0;

    const int MM = NDIM * NDIM;
    float* Ab = ws;
    float* P0 = Ab + MM;  float* P1 = P0 + MM;
    float* GA = P1 + MM;  float* GB = GA + MM;    // Ab^1024, Ab^2048
    float* GC = GB + MM;  float* GD = GC + MM;    // Ab^4096, Ab^8192
    float* V      = GD + MM;                      // 512 x 1024 (col j = v_j)
    float* Crows  = V + NDIM * TCH;               // 1024 x 512 (row j = c_j)
    float* CrowsS = Crows + TCH * NDIM;           // 1024 x 512 (aliases W)
    float* kv     = CrowsS + TCH * NDIM;          // 1024
    float* Bbc    = kv + TCH;                     // 512
    float* U      = Bbc + NDIM;                   // 16 x 512
    float* Z0     = U + PCH * NDIM;               // 16 x 512
    float* Z1     = Z0 + PCH * NDIM;              // 16 x 512
    float* Hmat   = Z1 + PCH * NDIM;              // 16 x 512
    float* W = CrowsS;   // W dead after phase C; CrowsS written at r>=10
    float* T = P0;       // T dead after pair level 256; P0 written at r=0

    // ---- phase A: zero strict-upper W + invert 8 diagonal blocks ----
    for (int idx = bid * NTH + tid; idx < MM; idx += NB * NTH) {
        int i = idx >> 9, j = idx & 511;
        if (j > i) W[idx] = 0.f;
    }
    if (bid < 8) diag_block_inv(smem, A, W, bid);
    ep++; grid_barrier(cnt, ep * NB);

    // ---- phase B: block-doubling combine W21 = dt/2 * W22 @ (A21 @ W11) ----
    for (int s = 64; s <= 256; s <<= 1) {
        const int tiles = (s >> 5) * (s >> 5);
        const int np = NDIM / (2 * s);
        for (int t = bid; t < np * tiles; t += NB) {
            int pr = t / tiles, tl = t % tiles, o = pr * 2 * s;
            gkt_core(smem, A + (size_t)(o + s) * NDIM + o, NDIM,
                     W + (size_t)o * NDIM + o, NDIM,
                     T + (size_t)(o + s) * NDIM + o, NDIM, s >> 5, tl, s, 1.f);
        }
        ep++; grid_barrier(cnt, ep * NB);
        for (int t = bid; t < np * tiles; t += NB) {
            int pr = t / tiles, tl = t % tiles, o = pr * 2 * s;
            gkt_core(smem, W + (size_t)(o + s) * NDIM + (o + s), NDIM,
                     T + (size_t)(o + s) * NDIM + o, NDIM,
                     W + (size_t)(o + s) * NDIM + o, NDIM, s >> 5, tl, s, DT2F);
        }
        ep++; grid_barrier(cnt, ep * NB);
    }

    // ---- phase C: Ab = 2W - I ; Bb = dt*W@Bv -> V[:,0],Bbc ; Crows[0]=C ----
    {
        int idx = bid * NTH + tid;            // first 128 blocks cover MM/4
        if (idx < MM / 4) {
            int i = idx >> 7, j0 = (idx & 127) << 2;
            float4 wv = *(const float4*)(W + (size_t)i * NDIM + j0);
            float4 r = make_float4(2.f * wv.x, 2.f * wv.y, 2.f * wv.z, 2.f * wv.w);
            if (i == j0)          r.x -= 1.f;
            else if (i == j0 + 1) r.y -= 1.f;
            else if (i == j0 + 2) r.z -= 1.f;
            else if (i == j0 + 3) r.w -= 1.f;
            *(float4*)(Ab + (size_t)i * NDIM + j0) = r;
        }
    }
    if (bid >= 128 && bid < 192) {            // prep: wave per row
        int i = (bid - 128) * 8 + w;
        float s = 0.f;
#pragma unroll
        for (int c2 = 0; c2 < 2; ++c2) {
            int k = c2 * 256 + lane * 4;
            float4 wv = *(const float4*)(W + (size_t)i * NDIM + k);
            float4 b4 = *(const float4*)(Bv + k);
            s += wv.x * b4.x + wv.y * b4.y + wv.z * b4.z + wv.w * b4.w;
        }
        s = wave_reduce(s);
        if (lane == 0) { float bb = DTF * s; V[(size_t)i * TCH] = bb; Bbc[i] = bb; }
    } else if (bid == 192) {
        Crows[tid] = C[tid];                  // 512 threads, 512 elements
    }
    ep++; grid_barrier(cnt, ep * NB);

    // ---- phase D: 13 doubling rounds (squaring + V/Crows doubling; post
    //      work rides in spare tasks at r>=10: CrowsS, kv, U) ----
    const float* gsrc = Ab;
    float* gouts[13] = {P0, P1, P0, P1, P0, P1, P0, P1, P0, GA, GB, GC, GD};
    for (int r = 0; r < 13; ++r) {
        const int m = 1 << r;
        float* gdst = gouts[r];
        int nextra;
        if (m < 32)        nextra = m * 9;                 // V-small + C-small
        else if (m < TCH)  nextra = 2 * ((m >> 5) * 16);   // V tiles + C tiles
        else               nextra = 555;                   // post quota
        const int ntasks = 256 + nextra;
        for (int t = bid; t < ntasks; t += NB) {
            if (t < 256) {
                gkt_core(smem, gsrc, NDIM, gsrc, NDIM, gdst, NDIM, 16, t, NDIM, 1.f);
            } else {
                int e = t - 256;
                if (m < 32) {
                    if (e < m * 8) {                       // V[:, m+j] = g @ V[:, j]
                        int j = e >> 3, slab = e & 7;
                        for (int k = tid; k < NDIM; k += NTH)
                            smem[k] = V[(size_t)k * TCH + j];
                        __syncthreads();
#pragma unroll
                        for (int d = 0; d < 8; ++d) {
                            int i = slab * 64 + w * 8 + d;
                            float ssum = 0.f;
#pragma unroll
                            for (int c2 = 0; c2 < 2; ++c2) {
                                int k = c2 * 256 + lane * 4;
                                float4 g4 = *(const float4*)(gsrc + (size_t)i * NDIM + k);
                                float4 v4 = *(const float4*)(smem + k);
                                ssum += g4.x * v4.x + g4.y * v4.y + g4.z * v4.z + g4.w * v4.w;
                            }
                            ssum = wave_reduce(ssum);
                            if (lane == 0) V[(size_t)i * TCH + m + j] = ssum;
                        }
                        __syncthreads();
                    } else {                               // Crows[m+j] = Crows[j] @ g
                        int j = e - m * 8;                 // 0..m-1
                        int c = tid;                       // 512 cols
                        const float* cr = Crows + (size_t)j * NDIM;
                        float acc = 0.f;
#pragma unroll 8
                        for (int k = 0; k < NDIM; ++k)
                            acc += cr[k] * gsrc[(size_t)k * NDIM + c];
                        Crows[(size_t)(m + j) * NDIM + c] = acc;
                    }
                } else if (m < TCH) {
                    const int nv = (m >> 5) * 16;
                    if (e < nv)
                        gkt_core(smem, gsrc, NDIM, V, TCH, V + m, TCH,
                                 m >> 5, e, NDIM, 1.f);
                    else
                        gkt_core(smem, Crows, NDIM, gsrc, NDIM,
                                 Crows + (size_t)m * NDIM, NDIM, 16, e - nv, NDIM, 1.f);
                } else {
                    int k = e * 3 + (r - 10);              // stride-3 interleave
                    if (k < 1664) {
                        if (k < 512) {                     // CrowsS tile
                            gkt_core(smem, Crows, NDIM, Ab, NDIM, CrowsS, NDIM,
                                     16, k, NDIM, 1.f);
                        } else if (k < 640) {              // kv group (8 j's)
                            int j = (k - 512) * 8 + w;
                            const float* cr = Crows + (size_t)j * NDIM;
                            float dot = 0.f;
#pragma unroll
                            for (int c2 = 0; c2 < 2; ++c2) {
                                int kk = c2 * 256 + lane * 4;
                                float4 cv = *(const float4*)(cr + kk);
                                float4 bv = *(const float4*)(Bbc + kk);
                                dot += cv.x * bv.x + cv.y * bv.y + cv.z * bv.z + cv.w * bv.w;
                            }
                            dot = wave_reduce(dot);
                            if (lane == 0) kv[j] = dot;
                        } else {                           // U group (+GA@h0 at p==0)
                            int wid = (k - 640) * 8 + w;   // 0..8191
                            int p = wid & (PCH - 1), i = wid >> 4;
                            const float* vr = V + (size_t)i * TCH;
                            const float* xc = x + p * TCH;
                            float s = 0.f;
#pragma unroll
                            for (int r2 = 0; r2 < 16; ++r2) {
                                int tt = (r2 << 6) + lane;
                                s += vr[TCH - 1 - tt] * xc[tt];
                            }
                            if (p == 0) {
                                const float* gr = GA + (size_t)i * NDIM;
#pragma unroll
                                for (int r2 = 0; r2 < 8; ++r2) {
                                    int kk = (r2 << 6) + lane;
                                    s += gr[kk] * hs[kk];
                                }
                            }
                            s = wave_reduce(s);
                            if (lane == 0) U[(size_t)p * NDIM + i] = s;
                        }
                    }
                }
            }
        }
        ep++; grid_barrier(cnt, ep * NB);
        gsrc = gdst;
    }

    // ---- phase E: Kogge-Stone chunk scan, offsets 1,2,4,8 ----
    {
        const float* Gs[4]  = {GA, GB, GC, GD};
        const float* Zi[4]  = {U, Z0, Z1, Z0};
        float*       Zo[4]  = {Z0, Z1, Z0, Z1};
        const int    os4[4] = {1, 2, 4, 8};
#pragma unroll
        for (int sr = 0; sr < 4; ++sr) {
            const float* G = Gs[sr]; const float* Zin = Zi[sr]; float* Zout = Zo[sr];
            const int o = os4[sr];
            for (int vt = bid; vt < 1024; vt += NB) {
                int wid = vt * 8 + w;                      // 0..8191
                int p = wid & (PCH - 1), i = wid >> 4;
                float dot = 0.f;
                if (p >= o) {
                    const float* gr = G + (size_t)i * NDIM;
                    const float* zc = Zin + (size_t)(p - o) * NDIM;
#pragma unroll
                    for (int r2 = 0; r2 < 8; ++r2) {
                        int k = (r2 << 6) + lane;
                        dot += gr[k] * zc[k];
                    }
                    dot = wave_reduce(dot);
                }
                if (lane == 0) {
                    float z = Zin[(size_t)p * NDIM + i] + dot;
                    Zout[(size_t)p * NDIM + i] = z;
                    if (sr == 3) {
                        if (p < PCH - 1) Hmat[(size_t)(p + 1) * NDIM + i] = z;
                        else             out[LSEQ + i] = z;
                        if (p == 0) Hmat[i] = hs[i];
                    }
                }
            }
            ep++; grid_barrier(cnt, ep * NB);
        }
    }

    // ---- phase F: emit y = c_{s+1}.h_p + causal conv ----
    for (int vt = bid; vt < 2048; vt += NB) {
        int wid = vt * 8 + w;                              // 0..16383
        int p = wid & (PCH - 1), s2 = wid >> 4;
        const float* cr = CrowsS + (size_t)s2 * NDIM;
        const float* hp = Hmat + (size_t)p * NDIM;
        float dot = 0.f;
#pragma unroll
        for (int r2 = 0; r2 < 2; ++r2) {
            int k = r2 * 256 + lane * 4;
            float4 cv = *(const float4*)(cr + k);
            float4 hv = *(const float4*)(hp + k);
            dot += cv.x * hv.x + cv.y * hv.y + cv.z * hv.z + cv.w * hv.w;
        }
        const float* xc = x + p * TCH;
        int rmax = s2 >> 6;
        for (int r2 = 0; r2 <= rmax; ++r2) {
            int t = (r2 << 6) + lane;
            if (t <= s2) dot += kv[s2 - t] * xc[t];
        }
        dot = wave_reduce(dot);
        if (lane == 0) out[p * TCH + s2] = dot;
    }
}

// ---------------------------------------------------------------------------
extern "C" void kernel_launch(void* const* d_in, const int* in_sizes, int n_in,
                              void* d_out, int out_size, void* d_ws, size_t ws_size,
                              hipStream_t stream)
{
    const float* x  = (const float*)d_in[0];
    const float* hs = (const float*)d_in[1];
    const float* A  = (const float*)d_in[2];
    const float* Bv = (const float*)d_in[3];
    const float* C  = (const float*)d_in[4];
    float* out = (float*)d_out;                 // [y (16384) | h_final (512)]
    float* ws  = (float*)d_ws;

    const size_t MM = (size_t)NDIM * NDIM;
    const size_t cnt_off = 7 * MM + 3 * (size_t)NDIM * TCH
                         + TCH + NDIM + 4 * (size_t)PCH * NDIM;
    unsigned* cnt = (unsigned*)(ws + cnt_off);
    hipMemsetAsync(cnt, 0, 256, stream);

    mega<<<NB, NTH, 0, stream>>>(x, hs, A, Bv, C, out, ws, cnt);
}

// Round 8
// 453.706 us; speedup vs baseline: 2.0332x; 1.8541x over previous
//
#include <hip/hip_runtime.h>

// N=512 state dim, L=16384 steps, chunk T=1024, P=16 chunks.
#define NDIM 512
#define LSEQ 16384
#define TCH  1024
#define PCH  16

#define DTF  (1.0f/16384.0f)
#define DT2F (0.5f/16384.0f)

__device__ __forceinline__ float wave_reduce(float v) {
#pragma unroll
    for (int off = 32; off; off >>= 1) v += __shfl_xor(v, off, 64);
    return v;
}

// ---------------------------------------------------------------------------
// gkt_core: 8-wave K-split GEMM tile, K=512. One 32x32 output tile per block;
// wave w covers k in [w*64,(w+1)*64) with private LDS staging; one barrier +
// cross-wave reduce. tmode=1: operands are read as (2*W - I) on the fly.
// ---------------------------------------------------------------------------
__device__ __forceinline__ void gkt_core(float* __restrict__ smem,
    const float* __restrict__ A, int lda, const float* __restrict__ B, int ldb,
    float* __restrict__ D, int ldd, int ntx, int tile_id, int tmode, float alpha)
{
    const int tid  = threadIdx.x;
    const int w    = tid >> 6;
    const int lane = tid & 63;
    const int ty = lane >> 3, tx = lane & 7;
    const int row0 = (tile_id / ntx) * 32, col0 = (tile_id % ntx) * 32;

    float* As = smem + w * 1152;          // As[k][r] = As[k*36 + r]
    float* Bs = As + 576;                 // Bs[k][c] = Bs[k*36 + c]
    const int kbase = w * 64;

    float acc[4][4] = {};

    for (int s = 0; s < 4; ++s) {
        const int kb = kbase + s * 16;
#pragma unroll
        for (int i = 0; i < 2; ++i) {     // stage A (transposed): 32 rows x 16 k
            int idx = lane + 64 * i;
            int r = idx >> 2, cg2 = (idx & 3) * 4;
            float4 v = *(const float4*)(A + (size_t)(row0 + r) * lda + kb + cg2);
            if (tmode) {
                int rr = row0 + r, cc = kb + cg2;
                v.x = 2.f * v.x - (rr == cc + 0 ? 1.f : 0.f);
                v.y = 2.f * v.y - (rr == cc + 1 ? 1.f : 0.f);
                v.z = 2.f * v.z - (rr == cc + 2 ? 1.f : 0.f);
                v.w = 2.f * v.w - (rr == cc + 3 ? 1.f : 0.f);
            }
            As[(cg2 + 0) * 36 + r] = v.x; As[(cg2 + 1) * 36 + r] = v.y;
            As[(cg2 + 2) * 36 + r] = v.z; As[(cg2 + 3) * 36 + r] = v.w;
        }
#pragma unroll
        for (int i = 0; i < 2; ++i) {     // stage B: 16 k x 32 cols
            int idx = lane + 64 * i;
            int kr = idx >> 3, cg2 = (idx & 7) * 4;
            float4 v = *(const float4*)(B + (size_t)(kb + kr) * ldb + col0 + cg2);
            if (tmode) {
                int rr = kb + kr, cc = col0 + cg2;
                v.x = 2.f * v.x - (rr == cc + 0 ? 1.f : 0.f);
                v.y = 2.f * v.y - (rr == cc + 1 ? 1.f : 0.f);
                v.z = 2.f * v.z - (rr == cc + 2 ? 1.f : 0.f);
                v.w = 2.f * v.w - (rr == cc + 3 ? 1.f : 0.f);
            }
            *(float4*)(Bs + kr * 36 + (cg2 - (cg2 & 3))) = v;   // cg2 already mult of 4
        }
        __syncthreads();
#pragma unroll
        for (int kk = 0; kk < 16; ++kk) {
            float4 a = *(const float4*)(As + kk * 36 + 4 * ty);
            float4 b = *(const float4*)(Bs + kk * 36 + 4 * tx);
            acc[0][0] += a.x * b.x; acc[0][1] += a.x * b.y; acc[0][2] += a.x * b.z; acc[0][3] += a.x * b.w;
            acc[1][0] += a.y * b.x; acc[1][1] += a.y * b.y; acc[1][2] += a.y * b.z; acc[1][3] += a.y * b.w;
            acc[2][0] += a.z * b.x; acc[2][1] += a.z * b.y; acc[2][2] += a.z * b.z; acc[2][3] += a.z * b.w;
            acc[3][0] += a.w * b.x; acc[3][1] += a.w * b.y; acc[3][2] += a.w * b.z; acc[3][3] += a.w * b.w;
        }
        __syncthreads();
    }

    float* red = smem + w * 1152;         // 32x32 partial per wave
#pragma unroll
    for (int i = 0; i < 4; ++i)
        *(float4*)(red + (4 * ty + i) * 32 + 4 * tx) =
            make_float4(acc[i][0], acc[i][1], acc[i][2], acc[i][3]);
    __syncthreads();

    if (tid < 256) {
        float4 s4 = make_float4(0.f, 0.f, 0.f, 0.f);
#pragma unroll
        for (int rr = 0; rr < 8; ++rr) {
            float4 p = *(const float4*)(smem + rr * 1152 + tid * 4);
            s4.x += p.x; s4.y += p.y; s4.z += p.z; s4.w += p.w;
        }
        s4.x *= alpha; s4.y *= alpha; s4.z *= alpha; s4.w *= alpha;
        int r = tid >> 3, c = (tid & 7) * 4;
        *(float4*)(D + (size_t)(row0 + r) * ldd + col0 + c) = s4;
    }
}

// ---------------------------------------------------------------------------
// k_diag64: block b owns rows [128b,128b+128). Zeros W's strict upper there,
// inverts the two 64x64 diagonal blocks of M = I - dt/2*A (wave0/wave1, lane
// j owns column j), then W21 = dt/2 * W22inv @ (A21 @ W11inv) fully in LDS.
// ---------------------------------------------------------------------------
__global__ __launch_bounds__(512) void k_diag64(const float* __restrict__ A,
                                                float* __restrict__ W)
{
    __shared__ float sh1[64][65];
    __shared__ float sh2[64][65];
    __shared__ float Ts[64][64];
    const int o = blockIdx.x * 128, tid = threadIdx.x;

    for (int idx = tid; idx < 128 * 512; idx += 512) {
        int i = o + (idx >> 9), j = idx & 511;
        if (j > i) W[(size_t)i * NDIM + j] = 0.f;
    }
    for (int idx = tid; idx < 4096; idx += 512) {
        int r = idx >> 6, c = idx & 63;
        float d = (r == c) ? 1.f : 0.f;
        sh1[r][c] = d - DT2F * A[(size_t)(o + r) * NDIM + o + c];
        sh2[r][c] = d - DT2F * A[(size_t)(o + 64 + r) * NDIM + o + 64 + c];
    }
    __syncthreads();
    if (tid < 128) {
        const int lane = tid & 63;
        float (*sh)[65] = (tid < 64) ? sh1 : sh2;
        const int gb = o + ((tid < 64) ? 0 : 64);
        float xcol[64];
#pragma unroll
        for (int i = 0; i < 64; ++i) {
            float dot = 0.f;
            for (int k = 0; k < i; ++k) dot += sh[i][k] * xcol[k];
            xcol[i] = (((lane == i) ? 1.f : 0.f) - dot) / sh[i][i];
        }
        for (int k = 0; k < 64; ++k)
            W[(size_t)(gb + k) * NDIM + gb + lane] = xcol[k];
        for (int k = 0; k < 64; ++k) sh[k][lane] = xcol[k];   // wave-sync safe
    }
    __syncthreads();
    for (int idx = tid; idx < 4096; idx += 512) {             // T = A21 @ W11inv
        int r = idx >> 6, c = idx & 63;
        const float* ar = A + (size_t)(o + 64 + r) * NDIM + o;
        float s = 0.f;
#pragma unroll 8
        for (int k = 0; k < 64; ++k) s += ar[k] * sh1[k][c];
        Ts[r][c] = s;
    }
    __syncthreads();
    for (int idx = tid; idx < 4096; idx += 512) {             // W21 = dt/2*W22inv@T
        int r = idx >> 6, c = idx & 63;
        float s = 0.f;
#pragma unroll 8
        for (int k = 0; k < 64; ++k) s += sh2[r][k] * Ts[k][c];
        W[(size_t)(o + 64 + r) * NDIM + o + c] = DT2F * s;
    }
}

// ---------------------------------------------------------------------------
// k_pair: one doubling level of the blocked inverse, pairA+pairB fused.
// Block = (pair, colgroup of cw=2^lgcw cols). Two-stage product via LDS:
//   Ts = A21 @ W11[:,cols] ; W21[:,cols] = dt/2 * W22 @ Ts.  s*cw == 2048.
// ---------------------------------------------------------------------------
__global__ __launch_bounds__(512) void k_pair(const float* __restrict__ A,
    float* __restrict__ W, int s, int lgcw)
{
    __shared__ float Ws[2048];
    __shared__ float Ts[2048];
    const int cw = 1 << lgcw, ncg = s >> lgcw;
    const int pr = blockIdx.x / ncg, cg = blockIdx.x % ncg;
    const int o = pr * 2 * s, c0 = cg * cw;
    const int tid = threadIdx.x;

    for (int idx = tid; idx < 2048; idx += 512) {
        int k = idx >> lgcw, c = idx & (cw - 1);
        Ws[idx] = W[(size_t)(o + k) * NDIM + o + c0 + c];
    }
    __syncthreads();
    for (int idx = tid; idx < 2048; idx += 512) {
        int r = idx >> lgcw, c = idx & (cw - 1);
        const float* ar = A + (size_t)(o + s + r) * NDIM + o;
        float acc = 0.f;
#pragma unroll 8
        for (int k = 0; k < s; ++k) acc += ar[k] * Ws[(k << lgcw) + c];
        Ts[idx] = acc;
    }
    __syncthreads();
    for (int idx = tid; idx < 2048; idx += 512) {
        int r = idx >> lgcw, c = idx & (cw - 1);
        const float* wr = W + (size_t)(o + s + r) * NDIM + o + s;
        float acc = 0.f;
#pragma unroll 8
        for (int k = 0; k < s; ++k) acc += wr[k] * Ts[(k << lgcw) + c];
        W[(size_t)(o + s + r) * NDIM + o + c0 + c] = DT2F * acc;
    }
}

// ---------------------------------------------------------------------------
// k_round1: P0 = Ab^2 via on-the-fly (2W-I) transform (256 tiles) +
// Ab = 2W - I (128 blocks) + prep (Bb, V[:,0], V[:,1], Bbc) + Crows rows 0,1.
// ---------------------------------------------------------------------------
__global__ __launch_bounds__(512) void k_round1(const float* __restrict__ W,
    float* __restrict__ P0, float* __restrict__ V, float* __restrict__ Crows,
    const float* __restrict__ Bv, const float* __restrict__ C,
    float* __restrict__ Ab, float* __restrict__ Bbc)
{
    __shared__ float smem[9216];
    const int t = blockIdx.x, tid = threadIdx.x;
    const int w = tid >> 6, lane = tid & 63;
    if (t < 256) {
        gkt_core(smem, W, NDIM, W, NDIM, P0, NDIM, 16, t, 1, 1.f);
    } else if (t < 384) {
        int idx = (t - 256) * 512 + tid;          // 65536 float4s total
        int i = idx >> 7, j0 = (idx & 127) << 2;
        float4 wv = *(const float4*)(W + (size_t)i * NDIM + j0);
        float4 r = make_float4(2.f * wv.x, 2.f * wv.y, 2.f * wv.z, 2.f * wv.w);
        if (i == j0)          r.x -= 1.f;
        else if (i == j0 + 1) r.y -= 1.f;
        else if (i == j0 + 2) r.z -= 1.f;
        else if (i == j0 + 3) r.w -= 1.f;
        *(float4*)(Ab + (size_t)i * NDIM + j0) = r;
    } else if (t == 384) {
        float* shBb = smem;                       // 512 floats
        for (int rr = 0; rr < 64; ++rr) {         // Bb = dt * W @ Bv
            int i = w * 64 + rr;
            float s = 0.f;
#pragma unroll
            for (int c2 = 0; c2 < 2; ++c2) {
                int k = c2 * 256 + lane * 4;
                float4 wv = *(const float4*)(W + (size_t)i * NDIM + k);
                float4 b4 = *(const float4*)(Bv + k);
                s += wv.x * b4.x + wv.y * b4.y + wv.z * b4.z + wv.w * b4.w;
            }
            s = wave_reduce(s);
            if (lane == 0) shBb[i] = DTF * s;
        }
        __syncthreads();
        for (int rr = 0; rr < 64; ++rr) {         // V1 = 2*W@Bb - Bb
            int i = w * 64 + rr;
            float s = 0.f;
#pragma unroll
            for (int c2 = 0; c2 < 2; ++c2) {
                int k = c2 * 256 + lane * 4;
                float4 wv = *(const float4*)(W + (size_t)i * NDIM + k);
                float4 b4 = *(const float4*)(shBb + k);
                s += wv.x * b4.x + wv.y * b4.y + wv.z * b4.z + wv.w * b4.w;
            }
            s = wave_reduce(s);
            if (lane == 0) {
                float bb = shBb[i];
                V[(size_t)i * TCH] = bb; Bbc[i] = bb;
                V[(size_t)i * TCH + 1] = 2.f * s - bb;
            }
        }
    } else {                                      // Crows rows 0,1
        float cv = C[tid];
        Crows[tid] = cv;
        float acc = 0.f;
#pragma unroll 8
        for (int k = 0; k < NDIM; ++k) acc += C[k] * W[(size_t)k * NDIM + tid];
        Crows[NDIM + tid] = 2.f * acc - cv;       // c_1 = C@Ab = 2*C@W - C
    }
}

// ---------------------------------------------------------------------------
// k_round: doubling round. t<256: gn = g@g. Extras: V[:,m:2m) = g@V[:,:m),
// Crows[m:2m) = Crows[:m)@g (matvec path for m<32, gkt tiles for m>=32).
// ---------------------------------------------------------------------------
__global__ __launch_bounds__(512) void k_round(const float* __restrict__ g,
    float* __restrict__ gn, float* __restrict__ V, float* __restrict__ Crows, int m)
{
    __shared__ float smem[9216];
    const int t = blockIdx.x, tid = threadIdx.x;
    const int w = tid >> 6, lane = tid & 63;
    if (t < 256) {
        gkt_core(smem, g, NDIM, g, NDIM, gn, NDIM, 16, t, 0, 1.f);
        return;
    }
    int e = t - 256;
    if (m < 32) {
        if (e < m * 8) {                          // V[:, m+j] = g @ V[:, j]
            int j = e >> 3, slab = e & 7;
            for (int k = tid; k < NDIM; k += 512) smem[k] = V[(size_t)k * TCH + j];
            __syncthreads();
#pragma unroll
            for (int d = 0; d < 8; ++d) {
                int i = slab * 64 + w * 8 + d;
                float s = 0.f;
#pragma unroll
                for (int c2 = 0; c2 < 2; ++c2) {
                    int k = c2 * 256 + lane * 4;
                    float4 g4 = *(const float4*)(g + (size_t)i * NDIM + k);
                    float4 v4 = *(const float4*)(smem + k);
                    s += g4.x * v4.x + g4.y * v4.y + g4.z * v4.z + g4.w * v4.w;
                }
                s = wave_reduce(s);
                if (lane == 0) V[(size_t)i * TCH + m + j] = s;
            }
        } else {                                  // Crows[m+j] = Crows[j] @ g
            int j = e - m * 8;
            const float* cr = Crows + (size_t)j * NDIM;
            float acc = 0.f;
#pragma unroll 8
            for (int k = 0; k < NDIM; ++k)
                acc += cr[k] * g[(size_t)k * NDIM + tid];
            Crows[(size_t)(m + j) * NDIM + tid] = acc;
        }
    } else {
        const int nv = (m >> 5) * 16;
        if (e < nv)
            gkt_core(smem, g, NDIM, V, TCH, V + m, TCH, m >> 5, e, 0, 1.f);
        else
            gkt_core(smem, Crows, NDIM, g, NDIM, Crows + (size_t)m * NDIM, NDIM,
                     16, e - nv, 0, 1.f);
    }
}

// ---------------------------------------------------------------------------
// k_post: GB = GA^2 (256) + CrowsS = Crows@Ab (512) + kv = Crows.Bb (128) +
// U[p][i] = V_rev.x_p (+ GA@h0 at p==0) (1024).  Grid 1920.
// ---------------------------------------------------------------------------
__global__ __launch_bounds__(512) void k_post(const float* __restrict__ GA,
    float* __restrict__ GB, const float* __restrict__ Crows,
    const float* __restrict__ Ab, float* __restrict__ CrowsS,
    const float* __restrict__ Bbc, float* __restrict__ kv,
    const float* __restrict__ V, const float* __restrict__ x,
    const float* __restrict__ hs, float* __restrict__ U)
{
    __shared__ float smem[9216];
    const int t = blockIdx.x, tid = threadIdx.x;
    const int w = tid >> 6, lane = tid & 63;
    if (t < 256) {
        gkt_core(smem, GA, NDIM, GA, NDIM, GB, NDIM, 16, t, 0, 1.f);
    } else if (t < 768) {
        gkt_core(smem, Crows, NDIM, Ab, NDIM, CrowsS, NDIM, 16, t - 256, 0, 1.f);
    } else if (t < 896) {
        int j = (t - 768) * 8 + w;
        const float* cr = Crows + (size_t)j * NDIM;
        float dot = 0.f;
#pragma unroll
        for (int c2 = 0; c2 < 2; ++c2) {
            int k = c2 * 256 + lane * 4;
            float4 cv = *(const float4*)(cr + k);
            float4 bv = *(const float4*)(Bbc + k);
            dot += cv.x * bv.x + cv.y * bv.y + cv.z * bv.z + cv.w * bv.w;
        }
        dot = wave_reduce(dot);
        if (lane == 0) kv[j] = dot;
    } else {
        int wid = (t - 896) * 8 + w;              // 0..8191
        int p = wid & (PCH - 1), i = wid >> 4;
        const float* vr = V + (size_t)i * TCH;
        const float* xc = x + p * TCH;
        float s = 0.f;
#pragma unroll
        for (int r2 = 0; r2 < 16; ++r2) {
            int tt = (r2 << 6) + lane;
            s += vr[TCH - 1 - tt] * xc[tt];
        }
        if (p == 0) {
            const float* gr = GA + (size_t)i * NDIM;
#pragma unroll
            for (int r2 = 0; r2 < 8; ++r2) {
                int k = (r2 << 6) + lane;
                s += gr[k] * hs[k];
            }
        }
        s = wave_reduce(s);
        if (lane == 0) U[(size_t)p * NDIM + i] = s;
    }
}

// ---------------------------------------------------------------------------
// k_sqscan: gn = g@g (256 tiles) + one Kogge-Stone scan round (1024 tasks).
// ---------------------------------------------------------------------------
__global__ __launch_bounds__(512) void k_sqscan(const float* __restrict__ g,
    float* __restrict__ gn, const float* __restrict__ G,
    const float* __restrict__ Zin, float* __restrict__ Zout, int o)
{
    __shared__ float smem[9216];
    const int t = blockIdx.x, tid = threadIdx.x;
    const int w = tid >> 6, lane = tid & 63;
    if (t < 256) {
        gkt_core(smem, g, NDIM, g, NDIM, gn, NDIM, 16, t, 0, 1.f);
        return;
    }
    int wid = (t - 256) * 8 + w;                  // 0..8191
    int p = wid & (PCH - 1), i = wid >> 4;
    float dot = 0.f;
    if (p >= o) {
        const float* gr = G + (size_t)i * NDIM;
        const float* zc = Zin + (size_t)(p - o) * NDIM;
#pragma unroll
        for (int r2 = 0; r2 < 8; ++r2) {
            int k = (r2 << 6) + lane;
            dot += gr[k] * zc[k];
        }
        dot = wave_reduce(dot);
    }
    if (lane == 0) Zout[(size_t)p * NDIM + i] = Zin[(size_t)p * NDIM + i] + dot;
}

// ---------------------------------------------------------------------------
// k_scan: scan round only (grid 1024); last=1 also emits Hmat and h_final.
// ---------------------------------------------------------------------------
__global__ __launch_bounds__(512) void k_scan(const float* __restrict__ G,
    const float* __restrict__ Zin, float* __restrict__ Zout,
    const float* __restrict__ hs, float* __restrict__ Hmat,
    float* __restrict__ hfin, int o, int last)
{
    const int tid = threadIdx.x, w = tid >> 6, lane = tid & 63;
    int wid = blockIdx.x * 8 + w;
    int p = wid & (PCH - 1), i = wid >> 4;
    float dot = 0.f;
    if (p >= o) {
        const float* gr = G + (size_t)i * NDIM;
        const float* zc = Zin + (size_t)(p - o) * NDIM;
#pragma unroll
        for (int r2 = 0; r2 < 8; ++r2) {
            int k = (r2 << 6) + lane;
            dot += gr[k] * zc[k];
        }
        dot = wave_reduce(dot);
    }
    if (lane == 0) {
        float z = Zin[(size_t)p * NDIM + i] + dot;
        Zout[(size_t)p * NDIM + i] = z;
        if (last) {
            if (p < PCH - 1) Hmat[(size_t)(p + 1) * NDIM + i] = z;
            else             hfin[i] = z;
            if (p == 0) Hmat[i] = hs[i];
        }
    }
}

// ---------------------------------------------------------------------------
// k_emit: y[p*T+s] = CrowsS[s].Hmat[p] + sum_{t<=s} kv[s-t]*x[p*T+t].
// ---------------------------------------------------------------------------
__global__ __launch_bounds__(512) void k_emit(const float* __restrict__ CrowsS,
    const float* __restrict__ Hmat, const float* __restrict__ kv,
    const float* __restrict__ x, float* __restrict__ out)
{
    const int tid = threadIdx.x, w = tid >> 6, lane = tid & 63;
    int wid = blockIdx.x * 8 + w;                 // 0..16383
    int p = wid & (PCH - 1), s2 = wid >> 4;
    const float* cr = CrowsS + (size_t)s2 * NDIM;
    const float* hp = Hmat + (size_t)p * NDIM;
    float dot = 0.f;
#pragma unroll
    for (int r2 = 0; r2 < 2; ++r2) {
        int k = r2 * 256 + lane * 4;
        float4 cv = *(const float4*)(cr + k);
        float4 hv = *(const float4*)(hp + k);
        dot += cv.x * hv.x + cv.y * hv.y + cv.z * hv.z + cv.w * hv.w;
    }
    const float* xc = x + p * TCH;
    int rmax = s2 >> 6;
    for (int r2 = 0; r2 <= rmax; ++r2) {
        int t = (r2 << 6) + lane;
        if (t <= s2) dot += kv[s2 - t] * xc[t];
    }
    dot = wave_reduce(dot);
    if (lane == 0) out[p * TCH + s2] = dot;
}

// ---------------------------------------------------------------------------
extern "C" void kernel_launch(void* const* d_in, const int* in_sizes, int n_in,
                              void* d_out, int out_size, void* d_ws, size_t ws_size,
                              hipStream_t stream)
{
    const float* x  = (const float*)d_in[0];
    const float* hs = (const float*)d_in[1];
    const float* A  = (const float*)d_in[2];
    const float* Bv = (const float*)d_in[3];
    const float* C  = (const float*)d_in[4];
    float* out = (float*)d_out;                 // [y (16384) | h_final (512)]

    const int MM = NDIM * NDIM;
    float* ws     = (float*)d_ws;
    float* Ab     = ws;
    float* P0     = Ab + MM;
    float* P1     = P0 + MM;
    float* GA     = P1 + MM;                    // Ab^1024
    float* GB     = GA + MM;                    // Ab^2048
    float* GC     = GB + MM;                    // Ab^4096
    float* GD     = GC + MM;                    // Ab^8192
    float* V      = GD + MM;                    // 512 x 1024
    float* Crows  = V + NDIM * TCH;             // 1024 x 512
    float* CrowsS = Crows + TCH * NDIM;         // 1024 x 512 (first 1MB = W)
    float* kv     = CrowsS + TCH * NDIM;        // 1024
    float* Bbc    = kv + TCH;                   // 512
    float* U      = Bbc + NDIM;                 // 16 x 512
    float* Z0     = U + PCH * NDIM;             // 16 x 512
    float* Z1     = Z0 + PCH * NDIM;            // 16 x 512
    float* Hmat   = Z1 + PCH * NDIM;            // 16 x 512

    float* W = CrowsS;  // W dead after k_round1; CrowsS first written in k_post

    // ---- blocked inverse of (I - dt/2 A): 3 dispatches ----
    k_diag64<<<4, 512, 0, stream>>>(A, W);
    k_pair<<<16, 512, 0, stream>>>(A, W, 128, 4);   // cw=16, 2 pairs x 8 cg
    k_pair<<<32, 512, 0, stream>>>(A, W, 256, 3);   // cw=8,  1 pair x 32 cg

    // ---- round 1 (fused form_ab/prep) + rounds 2..10 ----
    k_round1<<<386, 512, 0, stream>>>(W, P0, V, Crows, Bv, C, Ab, Bbc);
    const float* g = P0;
    float* outs[9] = {P1, P0, P1, P0, P1, P0, P1, P0, GA};
    int m = 2;
    for (int r = 0; r < 9; ++r) {
        int extras = (m < 32) ? m * 9 : m;
        k_round<<<256 + extras, 512, 0, stream>>>(g, outs[r], V, Crows, m);
        g = outs[r];
        m <<= 1;
    }

    // ---- post (GB + CrowsS + kv + U), then squarings fused with scans ----
    k_post<<<1920, 512, 0, stream>>>(GA, GB, Crows, Ab, CrowsS, Bbc, kv, V, x, hs, U);
    k_sqscan<<<1280, 512, 0, stream>>>(GB, GC, GA, U,  Z0, 1);
    k_sqscan<<<1280, 512, 0, stream>>>(GC, GD, GB, Z0, Z1, 2);
    k_scan<<<1024, 512, 0, stream>>>(GC, Z1, Z0, hs, Hmat, out + LSEQ, 4, 0);
    k_scan<<<1024, 512, 0, stream>>>(GD, Z0, Z1, hs, Hmat, out + LSEQ, 8, 1);

    // ---- fused epilogue ----
    k_emit<<<2048, 512, 0, stream>>>(CrowsS, Hmat, kv, x, out);
}

// Round 9
// 427.392 us; speedup vs baseline: 2.1584x; 1.0616x over previous
//
#include <hip/hip_runtime.h>

// N=512 state dim, L=16384 steps, chunk T=1024, P=16 chunks.
#define NDIM 512
#define LSEQ 16384
#define TCH  1024
#define PCH  16

#define DTF  (1.0f/16384.0f)
#define DT2F (0.5f/16384.0f)

__device__ __forceinline__ float wave_reduce(float v) {
#pragma unroll
    for (int off = 32; off; off >>= 1) v += __shfl_xor(v, off, 64);
    return v;
}

// ---------------------------------------------------------------------------
// gkt_core: 8-wave K-split GEMM tile, K=512. One 32x32 output tile per block;
// wave w covers k in [w*64,(w+1)*64) with private LDS staging; one barrier +
// cross-wave reduce. tmode=1: operands are read as (2*W - I) on the fly.
// ---------------------------------------------------------------------------
__device__ __forceinline__ void gkt_core(float* __restrict__ smem,
    const float* __restrict__ A, int lda, const float* __restrict__ B, int ldb,
    float* __restrict__ D, int ldd, int ntx, int tile_id, int tmode, float alpha)
{
    const int tid  = threadIdx.x;
    const int w    = tid >> 6;
    const int lane = tid & 63;
    const int ty = lane >> 3, tx = lane & 7;
    const int row0 = (tile_id / ntx) * 32, col0 = (tile_id % ntx) * 32;

    float* As = smem + w * 1152;          // As[k][r] = As[k*36 + r]
    float* Bs = As + 576;                 // Bs[k][c] = Bs[k*36 + c]
    const int kbase = w * 64;

    float acc[4][4] = {};

    for (int s = 0; s < 4; ++s) {
        const int kb = kbase + s * 16;
#pragma unroll
        for (int i = 0; i < 2; ++i) {     // stage A (transposed): 32 rows x 16 k
            int idx = lane + 64 * i;
            int r = idx >> 2, cg2 = (idx & 3) * 4;
            float4 v = *(const float4*)(A + (size_t)(row0 + r) * lda + kb + cg2);
            if (tmode) {
                int rr = row0 + r, cc = kb + cg2;
                v.x = 2.f * v.x - (rr == cc + 0 ? 1.f : 0.f);
                v.y = 2.f * v.y - (rr == cc + 1 ? 1.f : 0.f);
                v.z = 2.f * v.z - (rr == cc + 2 ? 1.f : 0.f);
                v.w = 2.f * v.w - (rr == cc + 3 ? 1.f : 0.f);
            }
            As[(cg2 + 0) * 36 + r] = v.x; As[(cg2 + 1) * 36 + r] = v.y;
            As[(cg2 + 2) * 36 + r] = v.z; As[(cg2 + 3) * 36 + r] = v.w;
        }
#pragma unroll
        for (int i = 0; i < 2; ++i) {     // stage B: 16 k x 32 cols
            int idx = lane + 64 * i;
            int kr = idx >> 3, cg2 = (idx & 7) * 4;
            float4 v = *(const float4*)(B + (size_t)(kb + kr) * ldb + col0 + cg2);
            if (tmode) {
                int rr = kb + kr, cc = col0 + cg2;
                v.x = 2.f * v.x - (rr == cc + 0 ? 1.f : 0.f);
                v.y = 2.f * v.y - (rr == cc + 1 ? 1.f : 0.f);
                v.z = 2.f * v.z - (rr == cc + 2 ? 1.f : 0.f);
                v.w = 2.f * v.w - (rr == cc + 3 ? 1.f : 0.f);
            }
            *(float4*)(Bs + kr * 36 + cg2) = v;
        }
        __syncthreads();
#pragma unroll
        for (int kk = 0; kk < 16; ++kk) {
            float4 a = *(const float4*)(As + kk * 36 + 4 * ty);
            float4 b = *(const float4*)(Bs + kk * 36 + 4 * tx);
            acc[0][0] += a.x * b.x; acc[0][1] += a.x * b.y; acc[0][2] += a.x * b.z; acc[0][3] += a.x * b.w;
            acc[1][0] += a.y * b.x; acc[1][1] += a.y * b.y; acc[1][2] += a.y * b.z; acc[1][3] += a.y * b.w;
            acc[2][0] += a.z * b.x; acc[2][1] += a.z * b.y; acc[2][2] += a.z * b.z; acc[2][3] += a.z * b.w;
            acc[3][0] += a.w * b.x; acc[3][1] += a.w * b.y; acc[3][2] += a.w * b.z; acc[3][3] += a.w * b.w;
        }
        __syncthreads();
    }

    float* red = smem + w * 1152;         // 32x32 partial per wave
#pragma unroll
    for (int i = 0; i < 4; ++i)
        *(float4*)(red + (4 * ty + i) * 32 + 4 * tx) =
            make_float4(acc[i][0], acc[i][1], acc[i][2], acc[i][3]);
    __syncthreads();

    if (tid < 256) {
        float4 s4 = make_float4(0.f, 0.f, 0.f, 0.f);
#pragma unroll
        for (int rr = 0; rr < 8; ++rr) {
            float4 p = *(const float4*)(smem + rr * 1152 + tid * 4);
            s4.x += p.x; s4.y += p.y; s4.z += p.z; s4.w += p.w;
        }
        s4.x *= alpha; s4.y *= alpha; s4.z *= alpha; s4.w *= alpha;
        int r = tid >> 3, c = (tid & 7) * 4;
        *(float4*)(D + (size_t)(row0 + r) * ldd + col0 + c) = s4;
    }
}

// ---------------------------------------------------------------------------
// diag_inv: blocks 0..7 invert the 64x64 diagonal blocks of M = I - dt/2*A
// into W (R2-proven form: 64 threads, static LDS array, register xcol —
// do NOT replace with a runtime-selected LDS pointer; that spills xcol to
// scratch and cost 69 us in R8). Blocks 8..39 zero W's strict upper
// (skipping intra-diag-block columns, which the inverter itself writes).
// ---------------------------------------------------------------------------
__global__ __launch_bounds__(64) void diag_inv(const float* __restrict__ A,
                                               float* __restrict__ W)
{
    const int b = blockIdx.x;
    const int lane = threadIdx.x;
    if (b >= 8) {                          // zero strict-upper, cross-block only
        int r0 = (b - 8) * 16;
        for (int r = 0; r < 16; ++r) {
            int i = r0 + r;
            int jstart = ((i >> 6) + 1) << 6;          // first col past own diag blk
            for (int j = jstart + lane; j < NDIM; j += 64)
                W[(size_t)i * NDIM + j] = 0.f;
        }
        return;
    }
    __shared__ float sh[64][65];
    const int base = b * 64;
    for (int r = 0; r < 64; ++r)
        sh[r][lane] = ((r == lane) ? 1.f : 0.f)
                    - DT2F * A[(size_t)(base + r) * NDIM + base + lane];
    __syncthreads();

    float xcol[64];
#pragma unroll
    for (int i = 0; i < 64; ++i) {
        float dot = 0.f;
#pragma unroll
        for (int k = 0; k < i; ++k) dot += sh[i][k] * xcol[k];
        xcol[i] = (((lane == i) ? 1.f : 0.f) - dot) / sh[i][i];
    }
#pragma unroll
    for (int k = 0; k < 64; ++k)
        W[(size_t)(base + k) * NDIM + base + lane] = xcol[k];
}

// ---------------------------------------------------------------------------
// k_pair: one doubling level of the blocked inverse, pairA+pairB fused.
// Block = (pair, colgroup of cw=2^lgcw cols). Two-stage product via LDS:
//   Ts = A21 @ W11[:,cols] ; W21[:,cols] = dt/2 * W22 @ Ts.  s*cw == 2048.
// ---------------------------------------------------------------------------
__global__ __launch_bounds__(512) void k_pair(const float* __restrict__ A,
    float* __restrict__ W, int s, int lgcw)
{
    __shared__ float Ws[2048];
    __shared__ float Ts[2048];
    const int cw = 1 << lgcw, ncg = s >> lgcw;
    const int pr = blockIdx.x / ncg, cg = blockIdx.x % ncg;
    const int o = pr * 2 * s, c0 = cg * cw;
    const int tid = threadIdx.x;

    for (int idx = tid; idx < 2048; idx += 512) {
        int k = idx >> lgcw, c = idx & (cw - 1);
        Ws[idx] = W[(size_t)(o + k) * NDIM + o + c0 + c];
    }
    __syncthreads();
    for (int idx = tid; idx < 2048; idx += 512) {
        int r = idx >> lgcw, c = idx & (cw - 1);
        const float* ar = A + (size_t)(o + s + r) * NDIM + o;
        float acc = 0.f;
#pragma unroll 8
        for (int k = 0; k < s; ++k) acc += ar[k] * Ws[(k << lgcw) + c];
        Ts[idx] = acc;
    }
    __syncthreads();
    for (int idx = tid; idx < 2048; idx += 512) {
        int r = idx >> lgcw, c = idx & (cw - 1);
        const float* wr = W + (size_t)(o + s + r) * NDIM + o + s;
        float acc = 0.f;
#pragma unroll 8
        for (int k = 0; k < s; ++k) acc += wr[k] * Ts[(k << lgcw) + c];
        W[(size_t)(o + s + r) * NDIM + o + c0 + c] = DT2F * acc;
    }
}

// ---------------------------------------------------------------------------
// k_round1: P0 = Ab^2 via on-the-fly (2W-I) transform (256 tiles) +
// Ab = 2W - I (128 blocks) + prep (Bb, V[:,0], V[:,1], Bbc) + Crows rows 0,1.
// ---------------------------------------------------------------------------
__global__ __launch_bounds__(512) void k_round1(const float* __restrict__ W,
    float* __restrict__ P0, float* __restrict__ V, float* __restrict__ Crows,
    const float* __restrict__ Bv, const float* __restrict__ C,
    float* __restrict__ Ab, float* __restrict__ Bbc)
{
    __shared__ float smem[9216];
    const int t = blockIdx.x, tid = threadIdx.x;
    const int w = tid >> 6, lane = tid & 63;
    if (t < 256) {
        gkt_core(smem, W, NDIM, W, NDIM, P0, NDIM, 16, t, 1, 1.f);
    } else if (t < 384) {
        int idx = (t - 256) * 512 + tid;          // 65536 float4s total
        int i = idx >> 7, j0 = (idx & 127) << 2;
        float4 wv = *(const float4*)(W + (size_t)i * NDIM + j0);
        float4 r = make_float4(2.f * wv.x, 2.f * wv.y, 2.f * wv.z, 2.f * wv.w);
        if (i == j0)          r.x -= 1.f;
        else if (i == j0 + 1) r.y -= 1.f;
        else if (i == j0 + 2) r.z -= 1.f;
        else if (i == j0 + 3) r.w -= 1.f;
        *(float4*)(Ab + (size_t)i * NDIM + j0) = r;
    } else if (t == 384) {
        float* shBb = smem;                       // 512 floats
        for (int rr = 0; rr < 64; ++rr) {         // Bb = dt * W @ Bv
            int i = w * 64 + rr;
            float s = 0.f;
#pragma unroll
            for (int c2 = 0; c2 < 2; ++c2) {
                int k = c2 * 256 + lane * 4;
                float4 wv = *(const float4*)(W + (size_t)i * NDIM + k);
                float4 b4 = *(const float4*)(Bv + k);
                s += wv.x * b4.x + wv.y * b4.y + wv.z * b4.z + wv.w * b4.w;
            }
            s = wave_reduce(s);
            if (lane == 0) shBb[i] = DTF * s;
        }
        __syncthreads();
        for (int rr = 0; rr < 64; ++rr) {         // V1 = 2*W@Bb - Bb
            int i = w * 64 + rr;
            float s = 0.f;
#pragma unroll
            for (int c2 = 0; c2 < 2; ++c2) {
                int k = c2 * 256 + lane * 4;
                float4 wv = *(const float4*)(W + (size_t)i * NDIM + k);
                float4 b4 = *(const float4*)(shBb + k);
                s += wv.x * b4.x + wv.y * b4.y + wv.z * b4.z + wv.w * b4.w;
            }
            s = wave_reduce(s);
            if (lane == 0) {
                float bb = shBb[i];
                V[(size_t)i * TCH] = bb; Bbc[i] = bb;
                V[(size_t)i * TCH + 1] = 2.f * s - bb;
            }
        }
    } else {                                      // Crows rows 0,1
        float cv = C[tid];
        Crows[tid] = cv;
        float acc = 0.f;
#pragma unroll 8
        for (int k = 0; k < NDIM; ++k) acc += C[k] * W[(size_t)k * NDIM + tid];
        Crows[NDIM + tid] = 2.f * acc - cv;       // c_1 = C@Ab = 2*C@W - C
    }
}

// ---------------------------------------------------------------------------
// k_round: doubling round. t<256: gn = g@g. Extras: V[:,m:2m) = g@V[:,:m),
// Crows[m:2m) = Crows[:m)@g (matvec path for m<32, gkt tiles for m>=32).
// ---------------------------------------------------------------------------
__global__ __launch_bounds__(512) void k_round(const float* __restrict__ g,
    float* __restrict__ gn, float* __restrict__ V, float* __restrict__ Crows, int m)
{
    __shared__ float smem[9216];
    const int t = blockIdx.x, tid = threadIdx.x;
    const int w = tid >> 6, lane = tid & 63;
    if (t < 256) {
        gkt_core(smem, g, NDIM, g, NDIM, gn, NDIM, 16, t, 0, 1.f);
        return;
    }
    int e = t - 256;
    if (m < 32) {
        if (e < m * 8) {                          // V[:, m+j] = g @ V[:, j]
            int j = e >> 3, slab = e & 7;
            for (int k = tid; k < NDIM; k += 512) smem[k] = V[(size_t)k * TCH + j];
            __syncthreads();
#pragma unroll
            for (int d = 0; d < 8; ++d) {
                int i = slab * 64 + w * 8 + d;
                float s = 0.f;
#pragma unroll
                for (int c2 = 0; c2 < 2; ++c2) {
                    int k = c2 * 256 + lane * 4;
                    float4 g4 = *(const float4*)(g + (size_t)i * NDIM + k);
                    float4 v4 = *(const float4*)(smem + k);
                    s += g4.x * v4.x + g4.y * v4.y + g4.z * v4.z + g4.w * v4.w;
                }
                s = wave_reduce(s);
                if (lane == 0) V[(size_t)i * TCH + m + j] = s;
            }
        } else {                                  // Crows[m+j] = Crows[j] @ g
            int j = e - m * 8;
            const float* cr = Crows + (size_t)j * NDIM;
            float acc = 0.f;
#pragma unroll 8
            for (int k = 0; k < NDIM; ++k)
                acc += cr[k] * g[(size_t)k * NDIM + tid];
            Crows[(size_t)(m + j) * NDIM + tid] = acc;
        }
    } else {
        const int nv = (m >> 5) * 16;
        if (e < nv)
            gkt_core(smem, g, NDIM, V, TCH, V + m, TCH, m >> 5, e, 0, 1.f);
        else
            gkt_core(smem, Crows, NDIM, g, NDIM, Crows + (size_t)m * NDIM, NDIM,
                     16, e - nv, 0, 1.f);
    }
}

// ---------------------------------------------------------------------------
// k_post: GB = GA^2 (256) + CrowsS = Crows@Ab (512) + kv = Crows.Bb (128) +
// U[p][i] = V_rev.x_p (+ GA@h0 at p==0) (1024).  Grid 1920.
// ---------------------------------------------------------------------------
__global__ __launch_bounds__(512) void k_post(const float* __restrict__ GA,
    float* __restrict__ GB, const float* __restrict__ Crows,
    const float* __restrict__ Ab, float* __restrict__ CrowsS,
    const float* __restrict__ Bbc, float* __restrict__ kv,
    const float* __restrict__ V, const float* __restrict__ x,
    const float* __restrict__ hs, float* __restrict__ U)
{
    __shared__ float smem[9216];
    const int t = blockIdx.x, tid = threadIdx.x;
    const int w = tid >> 6, lane = tid & 63;
    if (t < 256) {
        gkt_core(smem, GA, NDIM, GA, NDIM, GB, NDIM, 16, t, 0, 1.f);
    } else if (t < 768) {
        gkt_core(smem, Crows, NDIM, Ab, NDIM, CrowsS, NDIM, 16, t - 256, 0, 1.f);
    } else if (t < 896) {
        int j = (t - 768) * 8 + w;
        const float* cr = Crows + (size_t)j * NDIM;
        float dot = 0.f;
#pragma unroll
        for (int c2 = 0; c2 < 2; ++c2) {
            int k = c2 * 256 + lane * 4;
            float4 cv = *(const float4*)(cr + k);
            float4 bv = *(const float4*)(Bbc + k);
            dot += cv.x * bv.x + cv.y * bv.y + cv.z * bv.z + cv.w * bv.w;
        }
        dot = wave_reduce(dot);
        if (lane == 0) kv[j] = dot;
    } else {
        int wid = (t - 896) * 8 + w;              // 0..8191
        int p = wid & (PCH - 1), i = wid >> 4;
        const float* vr = V + (size_t)i * TCH;
        const float* xc = x + p * TCH;
        float s = 0.f;
#pragma unroll
        for (int r2 = 0; r2 < 16; ++r2) {
            int tt = (r2 << 6) + lane;
            s += vr[TCH - 1 - tt] * xc[tt];
        }
        if (p == 0) {
            const float* gr = GA + (size_t)i * NDIM;
#pragma unroll
            for (int r2 = 0; r2 < 8; ++r2) {
                int k = (r2 << 6) + lane;
                s += gr[k] * hs[k];
            }
        }
        s = wave_reduce(s);
        if (lane == 0) U[(size_t)p * NDIM + i] = s;
    }
}

// ---------------------------------------------------------------------------
// k_sqscan: gn = g@g (256 tiles) + one Kogge-Stone scan round (1024 tasks).
// ---------------------------------------------------------------------------
__global__ __launch_bounds__(512) void k_sqscan(const float* __restrict__ g,
    float* __restrict__ gn, const float* __restrict__ G,
    const float* __restrict__ Zin, float* __restrict__ Zout, int o)
{
    __shared__ float smem[9216];
    const int t = blockIdx.x, tid = threadIdx.x;
    const int w = tid >> 6, lane = tid & 63;
    if (t < 256) {
        gkt_core(smem, g, NDIM, g, NDIM, gn, NDIM, 16, t, 0, 1.f);
        return;
    }
    int wid = (t - 256) * 8 + w;                  // 0..8191
    int p = wid & (PCH - 1), i = wid >> 4;
    float dot = 0.f;
    if (p >= o) {
        const float* gr = G + (size_t)i * NDIM;
        const float* zc = Zin + (size_t)(p - o) * NDIM;
#pragma unroll
        for (int r2 = 0; r2 < 8; ++r2) {
            int k = (r2 << 6) + lane;
            dot += gr[k] * zc[k];
        }
        dot = wave_reduce(dot);
    }
    if (lane == 0) Zout[(size_t)p * NDIM + i] = Zin[(size_t)p * NDIM + i] + dot;
}

// ---------------------------------------------------------------------------
// k_scan: scan round only (grid 1024); last=1 also emits Hmat and h_final.
// ---------------------------------------------------------------------------
__global__ __launch_bounds__(512) void k_scan(const float* __restrict__ G,
    const float* __restrict__ Zin, float* __restrict__ Zout,
    const float* __restrict__ hs, float* __restrict__ Hmat,
    float* __restrict__ hfin, int o, int last)
{
    const int tid = threadIdx.x, w = tid >> 6, lane = tid & 63;
    int wid = blockIdx.x * 8 + w;
    int p = wid & (PCH - 1), i = wid >> 4;
    float dot = 0.f;
    if (p >= o) {
        const float* gr = G + (size_t)i * NDIM;
        const float* zc = Zin + (size_t)(p - o) * NDIM;
#pragma unroll
        for (int r2 = 0; r2 < 8; ++r2) {
            int k = (r2 << 6) + lane;
            dot += gr[k] * zc[k];
        }
        dot = wave_reduce(dot);
    }
    if (lane == 0) {
        float z = Zin[(size_t)p * NDIM + i] + dot;
        Zout[(size_t)p * NDIM + i] = z;
        if (last) {
            if (p < PCH - 1) Hmat[(size_t)(p + 1) * NDIM + i] = z;
            else             hfin[i] = z;
            if (p == 0) Hmat[i] = hs[i];
        }
    }
}

// ---------------------------------------------------------------------------
// k_emit: y[p*T+s] = CrowsS[s].Hmat[p] + sum_{t<=s} kv[s-t]*x[p*T+t].
// ---------------------------------------------------------------------------
__global__ __launch_bounds__(512) void k_emit(const float* __restrict__ CrowsS,
    const float* __restrict__ Hmat, const float* __restrict__ kv,
    const float* __restrict__ x, float* __restrict__ out)
{
    const int tid = threadIdx.x, w = tid >> 6, lane = tid & 63;
    int wid = blockIdx.x * 8 + w;                 // 0..16383
    int p = wid & (PCH - 1), s2 = wid >> 4;
    const float* cr = CrowsS + (size_t)s2 * NDIM;
    const float* hp = Hmat + (size_t)p * NDIM;
    float dot = 0.f;
#pragma unroll
    for (int r2 = 0; r2 < 2; ++r2) {
        int k = r2 * 256 + lane * 4;
        float4 cv = *(const float4*)(cr + k);
        float4 hv = *(const float4*)(hp + k);
        dot += cv.x * hv.x + cv.y * hv.y + cv.z * hv.z + cv.w * hv.w;
    }
    const float* xc = x + p * TCH;
    int rmax = s2 >> 6;
    for (int r2 = 0; r2 <= rmax; ++r2) {
        int t = (r2 << 6) + lane;
        if (t <= s2) dot += kv[s2 - t] * xc[t];
    }
    dot = wave_reduce(dot);
    if (lane == 0) out[p * TCH + s2] = dot;
}

// ---------------------------------------------------------------------------
extern "C" void kernel_launch(void* const* d_in, const int* in_sizes, int n_in,
                              void* d_out, int out_size, void* d_ws, size_t ws_size,
                              hipStream_t stream)
{
    const float* x  = (const float*)d_in[0];
    const float* hs = (const float*)d_in[1];
    const float* A  = (const float*)d_in[2];
    const float* Bv = (const float*)d_in[3];
    const float* C  = (const float*)d_in[4];
    float* out = (float*)d_out;                 // [y (16384) | h_final (512)]

    const int MM = NDIM * NDIM;
    float* ws     = (float*)d_ws;
    float* Ab     = ws;
    float* P0     = Ab + MM;
    float* P1     = P0 + MM;
    float* GA     = P1 + MM;                    // Ab^1024
    float* GB     = GA + MM;                    // Ab^2048
    float* GC     = GB + MM;                    // Ab^4096
    float* GD     = GC + MM;                    // Ab^8192
    float* V      = GD + MM;                    // 512 x 1024
    float* Crows  = V + NDIM * TCH;             // 1024 x 512
    float* CrowsS = Crows + TCH * NDIM;         // 1024 x 512 (first 1MB = W)
    float* kv     = CrowsS + TCH * NDIM;        // 1024
    float* Bbc    = kv + TCH;                   // 512
    float* U      = Bbc + NDIM;                 // 16 x 512
    float* Z0     = U + PCH * NDIM;             // 16 x 512
    float* Z1     = Z0 + PCH * NDIM;            // 16 x 512
    float* Hmat   = Z1 + PCH * NDIM;            // 16 x 512

    float* W = CrowsS;  // W dead after k_round1; CrowsS first written in k_post

    // ---- blocked inverse of (I - dt/2 A): 4 dispatches ----
    diag_inv<<<40, 64, 0, stream>>>(A, W);          // 8 invert + 32 zero-upper
    k_pair<<<8,  512, 0, stream>>>(A, W, 64, 5);    // cw=32, 4 pairs x 2 cg
    k_pair<<<16, 512, 0, stream>>>(A, W, 128, 4);   // cw=16, 2 pairs x 8 cg
    k_pair<<<32, 512, 0, stream>>>(A, W, 256, 3);   // cw=8,  1 pair x 32 cg

    // ---- round 1 (fused form_ab/prep) + rounds 2..10 ----
    k_round1<<<386, 512, 0, stream>>>(W, P0, V, Crows, Bv, C, Ab, Bbc);
    const float* g = P0;
    float* outs[9] = {P1, P0, P1, P0, P1, P0, P1, P0, GA};
    int m = 2;
    for (int r = 0; r < 9; ++r) {
        int extras = (m < 32) ? m * 9 : m;
        k_round<<<256 + extras, 512, 0, stream>>>(g, outs[r], V, Crows, m);
        g = outs[r];
        m <<= 1;
    }

    // ---- post (GB + CrowsS + kv + U), then squarings fused with scans ----
    k_post<<<1920, 512, 0, stream>>>(GA, GB, Crows, Ab, CrowsS, Bbc, kv, V, x, hs, U);
    k_sqscan<<<1280, 512, 0, stream>>>(GB, GC, GA, U,  Z0, 1);
    k_sqscan<<<1280, 512, 0, stream>>>(GC, GD, GB, Z0, Z1, 2);
    k_scan<<<1024, 512, 0, stream>>>(GC, Z1, Z0, hs, Hmat, out + LSEQ, 4, 0);
    k_scan<<<1024, 512, 0, stream>>>(GD, Z0, Z1, hs, Hmat, out + LSEQ, 8, 1);

    // ---- fused epilogue ----
    k_emit<<<2048, 512, 0, stream>>>(CrowsS, Hmat, kv, x, out);
}